// Round 13
// baseline (278.582 us; speedup 1.0000x reference)
//
#include <hip/hip_runtime.h>

#define S_LEN 2048
#define NHQ 32
#define NKV 8
#define HD 64
#define DMODEL 2048   // NHQ*HD
#define DKV 512       // NKV*HD

typedef unsigned short ushort_t;
typedef unsigned int uint_t;

typedef __attribute__((ext_vector_type(8))) short bf16x8;
typedef __attribute__((ext_vector_type(4))) float f32x4;

__device__ __forceinline__ float b2f(ushort_t h) {
  union { uint_t u; float f; } v;
  v.u = ((uint_t)h) << 16;
  return v.f;
}
// round-to-nearest-even fp32 -> bf16
__device__ __forceinline__ ushort_t f2b(float f) {
  union { float f; uint_t u; } v;
  v.f = f;
  uint_t r = v.u + 0x7fffu + ((v.u >> 16) & 1u);
  return (ushort_t)(r >> 16);
}
// HW packed fp32x2 -> bf16x2 (RNE); no builtin on gfx950, inline asm per guide T12
__device__ __forceinline__ uint_t cvt_pk_bf16(float lo, float hi) {
  uint_t r;
  asm("v_cvt_pk_bf16_f32 %0, %1, %2" : "=v"(r) : "v"(lo), "v"(hi));
  return r;
}

union BF8 { uint4 v; ushort_t s[8]; };

// async 16B global -> LDS (wave-uniform LDS base + lane*16)
__device__ __forceinline__ void gl_lds16(const ushort_t* g, ushort_t* l) {
  __builtin_amdgcn_global_load_lds((const __attribute__((address_space(1))) void*)g,
                                   (__attribute__((address_space(3))) void*)l, 16, 0, 0);
}

// 64x64 fp32->bf16 transpose tile body (shared by prework/postproj fusions).
// All 256 threads of the block must enter (contains __syncthreads).
__device__ __forceinline__ void wT_tile(const float* __restrict__ W,
                                        ushort_t* __restrict__ WT,
                                        int K, int N, int r0, int c0,
                                        ushort_t (*T)[66], int tid) {
  {
    const int rl = tid >> 2, cp = (tid & 3) * 16;
    const float* p = W + (size_t)(r0 + rl) * N + c0 + cp;
    float v[16];
    *(float4*)(v)      = *(const float4*)(p);
    *(float4*)(v + 4)  = *(const float4*)(p + 4);
    *(float4*)(v + 8)  = *(const float4*)(p + 8);
    *(float4*)(v + 12) = *(const float4*)(p + 12);
    #pragma unroll
    for (int j = 0; j < 16; ++j) T[cp + j][rl] = f2b(v[j]);
  }
  __syncthreads();
  {
    const int cl = tid >> 2, rp = (tid & 3) * 16;
    uint_t u[8];
    #pragma unroll
    for (int i = 0; i < 8; ++i) u[i] = *(const uint_t*)&T[cl][rp + 2 * i];
    ushort_t* outp = WT + (size_t)(c0 + cl) * K + r0 + rp;
    *(uint4*)(outp)     = make_uint4(u[0], u[1], u[2], u[3]);
    *(uint4*)(outp + 8) = make_uint4(u[4], u[5], u[6], u[7]);
  }
}

// Fused prework: blocks [0,2048) x->bf16; [2048,3072) wq^T; [3072,3328) wk^T;
// [3328,3584) wv^T. Branch is block-uniform; barriers only inside wT_tile.
__global__ __launch_bounds__(256) void prework(const float* __restrict__ X,
                                               ushort_t* __restrict__ XB,
                                               const float* __restrict__ Wq,
                                               const float* __restrict__ Wk,
                                               const float* __restrict__ Wv,
                                               ushort_t* __restrict__ WqT,
                                               ushort_t* __restrict__ WkvT) {
  __shared__ ushort_t T[64][66];
  const int tid = threadIdx.x;
  const int bid = blockIdx.x;
  if (bid < 2048) {
    int i = (bid * 256 + tid) * 8;
    float4 a = *(const float4*)(X + i);
    float4 b = *(const float4*)(X + i + 4);
    BF8 u;
    u.s[0] = f2b(a.x); u.s[1] = f2b(a.y); u.s[2] = f2b(a.z); u.s[3] = f2b(a.w);
    u.s[4] = f2b(b.x); u.s[5] = f2b(b.y); u.s[6] = f2b(b.z); u.s[7] = f2b(b.w);
    *(uint4*)(XB + i) = u.v;
    return;
  }
  const float* W; ushort_t* WT; int N; int local;
  if (bid < 3072)      { local = bid - 2048; W = Wq; WT = WqT;  N = DMODEL; }
  else if (bid < 3328) { local = bid - 3072; W = Wk; WT = WkvT; N = DKV; }
  else                 { local = bid - 3328; W = Wv; WT = WkvT + (size_t)DKV * DMODEL; N = DKV; }
  const int r0 = (local & 31) * 64, c0 = (local >> 5) * 64;
  wT_tile(W, WT, DMODEL, N, r0, c0, T, tid);
}

// Fused post-projection: blocks [0,1024) wo^T (into dead wqT region);
// [1024,3072) rope(K)+KB; [3072,3328) V transpose. All post-gemm_proj deps.
__global__ __launch_bounds__(256) void postproj(const float* __restrict__ Wo,
                                                ushort_t* __restrict__ WoT,
                                                float* Kio, ushort_t* __restrict__ KB,
                                                const float* __restrict__ cosT,
                                                const float* __restrict__ sinT,
                                                const float* __restrict__ V,
                                                ushort_t* __restrict__ VT) {
  __shared__ ushort_t T[64][66];
  const int tid = threadIdx.x;
  const int bid = blockIdx.x;
  if (bid < 1024) {
    const int r0 = (bid & 31) * 64, c0 = (bid >> 5) * 64;
    wT_tile(Wo, WoT, DMODEL, DMODEL, r0, c0, T, tid);
    return;
  }
  if (bid < 3072) {
    int idx = (bid - 1024) * 256 + tid;   // < S*8*32
    int d = idx & 31;
    int hk = (idx >> 5) & 7;
    int s = idx >> 8;
    float* p = Kio + (size_t)s * DKV + hk * HD + d;
    float x1 = p[0], x2 = p[32];
    float c = cosT[s * 64 + d], sn = sinT[s * 64 + d];
    float n1 = x1 * c - x2 * sn;
    float n2 = x1 * sn + x2 * c;
    p[0] = n1; p[32] = n2;
    ushort_t* kb = KB + (size_t)hk * S_LEN * HD + (size_t)s * HD + d;
    kb[0] = f2b(n1); kb[32] = f2b(n2);
    return;
  }
  {
    const int local = bid - 3072;
    const int s0 = (local & 31) * 64;
    const int hk = local >> 5;
    {
      const int s_l = tid >> 2, dp = (tid & 3) * 16;
      const float* p = V + (size_t)(s0 + s_l) * DKV + hk * HD + dp;
      float v[16];
      *(float4*)(v)      = *(const float4*)(p);
      *(float4*)(v + 4)  = *(const float4*)(p + 4);
      *(float4*)(v + 8)  = *(const float4*)(p + 8);
      *(float4*)(v + 12) = *(const float4*)(p + 12);
      #pragma unroll
      for (int j = 0; j < 16; ++j) T[dp + j][s_l] = f2b(v[j]);
    }
    __syncthreads();
    {
      const int d_l = tid >> 2, sp = (tid & 3) * 16;
      uint_t u[8];
      #pragma unroll
      for (int i = 0; i < 8; ++i) u[i] = *(const uint_t*)&T[d_l][sp + 2 * i];
      ushort_t* outp = VT + (size_t)hk * HD * S_LEN + (size_t)d_l * S_LEN + s0 + sp;
      *(uint4*)(outp)     = make_uint4(u[0], u[1], u[2], u[3]);
      *(uint4*)(outp + 8) = make_uint4(u[4], u[5], u[6], u[7]);
    }
  }
}

// GEMM core (round-9 best, exact): 128(M)x128(N) tile, BK=64, 8 waves,
// double-buffered. 32 barrier-drains per block — the proven lever (289->267).
// K-halves stored as separate [128][32] sub-tiles to keep the verified m97
// staging/ds_read layout. The r10 counted-vmcnt graft and the r11 XCD swizzle
// both regressed and are deleted.
__device__ __forceinline__ void gemm_core_db64(const ushort_t* __restrict__ A,
                                               const ushort_t* __restrict__ BT,
                                               int K, int tile_m, int tile_n,
                                               f32x4 (&acc)[4][2],
                                               ushort_t* AsBase,  // [2][2][128][32]
                                               ushort_t* BsBase) {
  const int tid = threadIdx.x;
  const int lane = tid & 63;
  const int w = tid >> 6;                       // 0..7
  const int wr = (w >> 2) * 64, wc = (w & 3) * 32;
  const int lm = lane & 15, kq = lane >> 4;
  const int BUF = 2 * 128 * 32;                 // ushorts per buffer (2 halves)
  const int HALF = 128 * 32;                    // ushorts per half-tile

  #pragma unroll
  for (int i = 0; i < 4; ++i)
    #pragma unroll
    for (int j = 0; j < 2; ++j) acc[i][j] = {0.f, 0.f, 0.f, 0.f};

  // per-lane global sources; lane l -> row w*16 + (l>>2), k-col (l&3)*8
  const ushort_t* ap = A  + (size_t)(tile_m + w * 16 + (lane >> 2)) * K + (lane & 3) * 8;
  const ushort_t* bp = BT + (size_t)(tile_n + w * 16 + (lane >> 2)) * K + (lane & 3) * 8;
  // wave-uniform LDS stage bases (rows w*16..w*16+15 of each half)
  ushort_t* asw = AsBase + w * 512;
  ushort_t* bsw = BsBase + w * 512;

  // prologue: stage kt=0, both halves, into buf 0
  gl_lds16(ap,      asw);
  gl_lds16(ap + 32, asw + HALF);
  gl_lds16(bp,      bsw);
  gl_lds16(bp + 32, bsw + HALF);
  __syncthreads();                              // buf0 ready

  int cur = 0;
  for (int kt = 0; kt < K; kt += 64) {
    if (kt + 64 < K) {
      const int nb = (cur ^ 1) * BUF;
      gl_lds16(ap + kt + 64, asw + nb);
      gl_lds16(ap + kt + 96, asw + nb + HALF);
      gl_lds16(bp + kt + 64, bsw + nb);
      gl_lds16(bp + kt + 96, bsw + nb + HALF);
    }
    const ushort_t* ac = AsBase + cur * BUF;
    const ushort_t* bc = BsBase + cur * BUF;
    #pragma unroll
    for (int kc = 0; kc < 2; ++kc) {
      bf16x8 af[4], bfr[2];
      #pragma unroll
      for (int i = 0; i < 4; ++i)
        af[i]  = *(const bf16x8*)(ac + kc * HALF + (wr + 16 * i + lm) * 32 + kq * 8);
      #pragma unroll
      for (int j = 0; j < 2; ++j)
        bfr[j] = *(const bf16x8*)(bc + kc * HALF + (wc + 16 * j + lm) * 32 + kq * 8);
      #pragma unroll
      for (int i = 0; i < 4; ++i)
        #pragma unroll
        for (int j = 0; j < 2; ++j)
          acc[i][j] = __builtin_amdgcn_mfma_f32_16x16x32_bf16(af[i], bfr[j], acc[i][j], 0, 0, 0);
    }
    __syncthreads();   // drains vmcnt (next buf staged) + lgkm (cur reads done)
    cur ^= 1;
  }
}

// Fused q/k/v projection: BT = [wqT|wkT|wvT] (N=3072). Split epilogue.
__global__ __launch_bounds__(512) void gemm_proj(const ushort_t* __restrict__ A,
                                                 const ushort_t* __restrict__ BT,
                                                 ushort_t* __restrict__ Qo,
                                                 float* __restrict__ Ko,
                                                 float* __restrict__ Vo) {
  __shared__ ushort_t As[2][2][128][32];
  __shared__ ushort_t Bs[2][2][128][32];
  const int lane = threadIdx.x & 63;
  const int w = threadIdx.x >> 6;
  const int wr = (w >> 2) * 64, wc = (w & 3) * 32;
  const int lm = lane & 15, kq = lane >> 4;
  const int tile_m = blockIdx.y * 128, tile_n = blockIdx.x * 128;
  f32x4 acc[4][2];
  gemm_core_db64(A, BT, DMODEL, tile_m, tile_n, acc, &As[0][0][0][0], &Bs[0][0][0][0]);
  #pragma unroll
  for (int i = 0; i < 4; ++i)
    #pragma unroll
    for (int j = 0; j < 2; ++j)
      #pragma unroll
      for (int r = 0; r < 4; ++r) {
        const int row = tile_m + wr + 16 * i + kq * 4 + r;
        const int col = tile_n + wc + 16 * j + lm;
        const float v = acc[i][j][r];
        if (col < 2048)      Qo[(size_t)row * DMODEL + col] = f2b(v);
        else if (col < 2560) Ko[(size_t)row * DKV + col - 2048] = v;
        else                 Vo[(size_t)row * DKV + col - 2560] = v;
      }
}

// Final projection: C fp32 [M][2048]
__global__ __launch_bounds__(512) void gemm_out(const ushort_t* __restrict__ A,
                                                const ushort_t* __restrict__ BT,
                                                float* __restrict__ C) {
  __shared__ ushort_t As[2][2][128][32];
  __shared__ ushort_t Bs[2][2][128][32];
  const int lane = threadIdx.x & 63;
  const int w = threadIdx.x >> 6;
  const int wr = (w >> 2) * 64, wc = (w & 3) * 32;
  const int lm = lane & 15, kq = lane >> 4;
  const int tile_m = blockIdx.y * 128, tile_n = blockIdx.x * 128;
  f32x4 acc[4][2];
  gemm_core_db64(A, BT, DMODEL, tile_m, tile_n, acc, &As[0][0][0][0], &Bs[0][0][0][0]);
  #pragma unroll
  for (int i = 0; i < 4; ++i)
    #pragma unroll
    for (int j = 0; j < 2; ++j)
      #pragma unroll
      for (int r = 0; r < 4; ++r) {
        const int row = tile_m + wr + 16 * i + kq * 4 + r;
        const int col = tile_n + wc + 16 * j + lm;
        C[(size_t)row * DMODEL + col] = acc[i][j][r];
      }
}

// MFMA flash attention v8: v7 + s_setprio(1) around both MFMA clusters (T5).
// Mechanism (m191): 4 barrier-free waves per block at skewed trip counts +
// independent blocks on the CU -> non-lockstep wave mix; setprio lets the
// scheduler favor the MFMA-entering wave. (m190's null was lockstep GEMM.)
// XCD-pinned KV heads: hk = bid&7 -> per-XCD K/V = 512KB, L2-resident.
__global__ __launch_bounds__(256, 4) void attn_mfma8(const ushort_t* Q,
                                                     const ushort_t* __restrict__ KB,
                                                     const ushort_t* __restrict__ VT,
                                                     const float* __restrict__ cosT,
                                                     const float* __restrict__ sinT,
                                                     ushort_t* O) {
  // union: loop phase Ps[4][32][72] ushort (18432B);
  // combine phase f32 Co[2][64][36] (18432B) + Cm[2][2][64] + Cl[2][2][64] (2048B)
  __shared__ __align__(16) char smem[20480];
  ushort_t (*Ps)[32][72] = (ushort_t (*)[32][72])smem;
  const int wv = threadIdx.x >> 6;          // 0..3
  const int lane = threadIdx.x & 63;
  const int lm = lane & 15, kq = lane >> 4;
  const int bid = blockIdx.x;
  const int xcd = bid & 7;                  // empirical XCD id (bid % 8)
  const int idx = bid >> 3;                 // 0..255 within this XCD
  const int h = (xcd << 2) | (idx & 3);     // hk = h>>2 = xcd: KV pinned to XCD
  const int g = 63 - (idx >> 2);            // LPT within XCD
  const int q0 = g * 32;
  const int hk = h >> 2;
  const ushort_t* KBh = KB + (size_t)hk * S_LEN * HD;
  const ushort_t* VTh = VT + (size_t)hk * HD * S_LEN;
  const float SCL = 0.125f * 1.44269504f;   // /sqrt(64) * log2(e), folded into Q

  // hoisted Q B-frags with in-register RoPE, pre-scaled by SCL
  bf16x8 bq[2][2];
  #pragma unroll
  for (int nt = 0; nt < 2; ++nt) {
    const int row = q0 + 16 * nt + lm;
    const ushort_t* qp = Q + (size_t)row * DMODEL + h * HD + 8 * kq;
    bf16x8 x1v = *(const bf16x8*)qp;
    bf16x8 x2v = *(const bf16x8*)(qp + 32);
    const float* cp = cosT + row * 64 + 8 * kq;
    const float* sp = sinT + row * 64 + 8 * kq;
    float c[8], s[8];
    *(float4*)(c)     = *(const float4*)(cp);
    *(float4*)(c + 4) = *(const float4*)(cp + 4);
    *(float4*)(s)     = *(const float4*)(sp);
    *(float4*)(s + 4) = *(const float4*)(sp + 4);
    BF8 o1, o2;
    #pragma unroll
    for (int j = 0; j < 8; ++j) {
      float x1 = b2f((ushort_t)x1v[j]);
      float x2 = b2f((ushort_t)x2v[j]);
      o1.s[j] = f2b((x1 * c[j] - x2 * s[j]) * SCL);
      o2.s[j] = f2b((x1 * s[j] + x2 * c[j]) * SCL);
    }
    bq[nt][0] = *(const bf16x8*)&o1;
    bq[nt][1] = *(const bf16x8*)&o2;
  }

  f32x4 Oa[4][2];
  #pragma unroll
  for (int mt = 0; mt < 4; ++mt) { Oa[mt][0] = {0.f,0.f,0.f,0.f}; Oa[mt][1] = {0.f,0.f,0.f,0.f}; }
  float m[2] = {-1e30f, -1e30f};
  float l[2] = {0.f, 0.f};                  // per-lane PARTIAL sums (quadrant-local)

  const int ntiles = (g >> 1) + 1;
  for (int t = wv; t < ntiles; t += 4) {
    const int base = t * 64;
    f32x4 sc[4][2];
    #pragma unroll
    for (int mt = 0; mt < 4; ++mt) { sc[mt][0] = {0.f,0.f,0.f,0.f}; sc[mt][1] = {0.f,0.f,0.f,0.f}; }
    #pragma unroll
    for (int kc = 0; kc < 2; ++kc) {
      bf16x8 ak[4];
      #pragma unroll
      for (int mt = 0; mt < 4; ++mt)
        ak[mt] = *(const bf16x8*)&KBh[(size_t)(base + 16 * mt + lm) * HD + 8 * kq + 32 * kc];
      __builtin_amdgcn_s_setprio(1);
      #pragma unroll
      for (int mt = 0; mt < 4; ++mt)
        #pragma unroll
        for (int nt = 0; nt < 2; ++nt)
          sc[mt][nt] = __builtin_amdgcn_mfma_f32_16x16x32_bf16(ak[mt], bq[nt][kc], sc[mt][nt], 0, 0, 0);
      __builtin_amdgcn_s_setprio(0);
    }
    const bool diag = (t == ntiles - 1);
    #pragma unroll
    for (int nt = 0; nt < 2; ++nt) {
      const int qg = q0 + 16 * nt + lm;
      if (diag) {
        #pragma unroll
        for (int mt = 0; mt < 4; ++mt)
          #pragma unroll
          for (int r = 0; r < 4; ++r)
            if (base + 16 * mt + 4 * kq + r > qg) sc[mt][nt][r] = -1e9f;
      }
      // per-lane local max; the __all ballot IS the global defer-max check
      float lmx = sc[0][nt][0];
      #pragma unroll
      for (int mt = 0; mt < 4; ++mt)
        #pragma unroll
        for (int r = 0; r < 4; ++r) lmx = fmaxf(lmx, sc[mt][nt][r]);
      if (!__all(lmx <= m[nt] + 8.f)) {   // rare path: true new max, rescale
        float mx = fmaxf(lmx, __shfl_xor(lmx, 16));
        mx = fmaxf(mx, __shfl_xor(mx, 32));
        const float mn = fmaxf(m[nt], mx);
        const float al = exp2f(m[nt] - mn);
        m[nt] = mn;
        l[nt] *= al;
        #pragma unroll
        for (int mt = 0; mt < 4; ++mt)
          #pragma unroll
          for (int r = 0; r < 4; ++r) Oa[mt][nt][r] *= al;
      }
      float sum = 0.f;
      #pragma unroll
      for (int mt = 0; mt < 4; ++mt)
        #pragma unroll
        for (int r = 0; r < 4; ++r) {
          float p = exp2f(sc[mt][nt][r] - m[nt]);
          sc[mt][nt][r] = p;
          sum += p;
        }
      l[nt] += sum;                        // partial; cross-lane reduce after loop
      ushort_t* pw = &Ps[wv][16 * nt + lm][4 * kq];
      #pragma unroll
      for (int mt = 0; mt < 4; ++mt)
        *(uint2*)(pw + 16 * mt) = make_uint2(cvt_pk_bf16(sc[mt][nt][0], sc[mt][nt][1]),
                                             cvt_pk_bf16(sc[mt][nt][2], sc[mt][nt][3]));
    }
    #pragma unroll
    for (int kc = 0; kc < 2; ++kc) {
      bf16x8 av[4], pb[2];
      #pragma unroll
      for (int mt = 0; mt < 4; ++mt)
        av[mt] = *(const bf16x8*)&VTh[(size_t)(16 * mt + lm) * S_LEN + base + 8 * kq + 32 * kc];
      #pragma unroll
      for (int nt = 0; nt < 2; ++nt)
        pb[nt] = *(const bf16x8*)&Ps[wv][16 * nt + lm][8 * kq + 32 * kc];   // 16B aligned
      __builtin_amdgcn_s_setprio(1);
      #pragma unroll
      for (int mt = 0; mt < 4; ++mt)
        #pragma unroll
        for (int nt = 0; nt < 2; ++nt)
          Oa[mt][nt] = __builtin_amdgcn_mfma_f32_16x16x32_bf16(av[mt], pb[nt], Oa[mt][nt], 0, 0, 0);
      __builtin_amdgcn_s_setprio(0);
    }
  }
  // finalize per-wave l: cross-quadrant sum (once, not per tile)
  #pragma unroll
  for (int nt = 0; nt < 2; ++nt) {
    l[nt] += __shfl_xor(l[nt], 16);
    l[nt] += __shfl_xor(l[nt], 32);
  }

  // ---- two-stage 2-slot flash-combine ----
  float* CoB = (float*)smem;                  // [2][64][36]
  float* CmB = (float*)smem + 2 * 64 * 36;    // [2][2][64]
  float* ClB = CmB + 2 * 2 * 64;              // [2][2][64]
  __syncthreads();                            // all Ps reads done; smem reused
  if (wv & 1) {                               // waves 1,3 store
    const int slot = wv >> 1;
    float* myo = CoB + (size_t)(slot * 64 + lane) * 36;
    #pragma unroll
    for (int mt = 0; mt < 4; ++mt)
      #pragma unroll
      for (int nt = 0; nt < 2; ++nt)
        *(f32x4*)(myo + (mt * 2 + nt) * 4) = Oa[mt][nt];
    #pragma unroll
    for (int nt = 0; nt < 2; ++nt) {
      CmB[(slot * 2 + nt) * 64 + lane] = m[nt];
      ClB[(slot * 2 + nt) * 64 + lane] = l[nt];
    }
  }
  __syncthreads();
  if (!(wv & 1)) {                            // waves 0,2 merge their slot
    const int slot = wv >> 1;
    const float* po = CoB + (size_t)(slot * 64 + lane) * 36;
    #pragma unroll
    for (int nt = 0; nt < 2; ++nt) {
      const float m1 = CmB[(slot * 2 + nt) * 64 + lane];
      const float l1 = ClB[(slot * 2 + nt) * 64 + lane];
      const float mn = fmaxf(m[nt], m1);
      const float a0 = exp2f(m[nt] - mn);
      const float a1 = exp2f(m1 - mn);
      m[nt] = mn;
      l[nt] = l[nt] * a0 + l1 * a1;
      #pragma unroll
      for (int mt = 0; mt < 4; ++mt) {
        const f32x4 ov = *(const f32x4*)(po + (mt * 2 + nt) * 4);
        #pragma unroll
        for (int r = 0; r < 4; ++r) Oa[mt][nt][r] = Oa[mt][nt][r] * a0 + ov[r] * a1;
      }
    }
  }
  __syncthreads();
  if (wv == 2) {                              // stage 2 store
    float* myo = CoB + (size_t)lane * 36;
    #pragma unroll
    for (int mt = 0; mt < 4; ++mt)
      #pragma unroll
      for (int nt = 0; nt < 2; ++nt)
        *(f32x4*)(myo + (mt * 2 + nt) * 4) = Oa[mt][nt];
    #pragma unroll
    for (int nt = 0; nt < 2; ++nt) {
      CmB[nt * 64 + lane] = m[nt];
      ClB[nt * 64 + lane] = l[nt];
    }
  }
  __syncthreads();
  if (wv == 0) {                              // final merge + output
    const float* po = CoB + (size_t)lane * 36;
    #pragma unroll
    for (int nt = 0; nt < 2; ++nt) {
      const float m1 = CmB[nt * 64 + lane];
      const float l1 = ClB[nt * 64 + lane];
      const float mn = fmaxf(m[nt], m1);
      const float a0 = exp2f(m[nt] - mn);
      const float a1 = exp2f(m1 - mn);
      const float inv = 1.f / (l[nt] * a0 + l1 * a1);
      ushort_t* orow = O + (size_t)(q0 + 16 * nt + lm) * DMODEL + h * HD + 4 * kq;
      #pragma unroll
      for (int mt = 0; mt < 4; ++mt) {
        const f32x4 ov = *(const f32x4*)(po + (mt * 2 + nt) * 4);
        const float v0 = (Oa[mt][nt][0] * a0 + ov[0] * a1) * inv;
        const float v1 = (Oa[mt][nt][1] * a0 + ov[1] * a1) * inv;
        const float v2 = (Oa[mt][nt][2] * a0 + ov[2] * a1) * inv;
        const float v3 = (Oa[mt][nt][3] * a0 + ov[3] * a1) * inv;
        *(uint2*)(orow + 16 * mt) = make_uint2(cvt_pk_bf16(v0, v1), cvt_pk_bf16(v2, v3));
      }
    }
  }
}

extern "C" void kernel_launch(void* const* d_in, const int* in_sizes, int n_in,
                              void* d_out, int out_size, void* d_ws, size_t ws_size,
                              hipStream_t stream) {
  const float* x    = (const float*)d_in[0];
  const float* cosT = (const float*)d_in[1];
  const float* sinT = (const float*)d_in[2];
  // d_in[3] = mask: causal -1e9, applied analytically (identical semantics)
  const float* wq   = (const float*)d_in[4];
  const float* wk   = (const float*)d_in[5];
  const float* wv   = (const float*)d_in[6];
  const float* wo   = (const float*)d_in[7];

  float* out   = (float*)d_out;                    // [S, 2048] fp32
  float* out_k = out + (size_t)S_LEN * DMODEL;     // new_k [S, 8, 64] fp32
  float* out_v = out_k + (size_t)S_LEN * DKV;      // new_v [S, 8, 64] fp32

  const size_t MB = 1024 * 1024;
  ushort_t* ws    = (ushort_t*)d_ws;               // ws_size >= 24 MB (confirmed r8)
  ushort_t* wqT   = ws;                            // [0,8M)  wqT bf16 [2048][2048]; later woT
  ushort_t* wkT   = ws + 4 * MB;                   // [8,10M) wkT; wvT follows -> BT [3072][2048]
  ushort_t* ws_q  = ws + 6 * MB;                   // [12,20M) q bf16 [S][2048]
  ushort_t* ws_kb = ws + 10 * MB;                  // [20,22M) KB bf16 [8][S][64]
  ushort_t* ws_vt = ws + 11 * MB;                  // [22,24M) VT bf16 [8][64][S]
  ushort_t* xb    = (ushort_t*)out;                // scratch in dead out region

  dim3 blk(256);
  dim3 blk8(512);
  // fused prework: x->bf16 + wq/wk/wv transposes (1 launch)
  prework<<<3584, blk, 0, stream>>>(x, xb, wq, wk, wv, wqT, wkT);
  // fused q/k/v projection (N = 3072), 128x128 tiles, BK=64 dbuf pipeline
  gemm_proj<<<dim3(3072 / 128, S_LEN / 128), blk8, 0, stream>>>(xb, wqT, ws_q, out_k, out_v);
  // fused post-proj: wo^T (into dead wqT) + rope(K)+KB + V transpose (1 launch)
  postproj<<<3328, blk, 0, stream>>>(wo, wqT, out_k, ws_kb, cosT, sinT, out_v, ws_vt);
  // attention v8: XCD-pinned KV heads + setprio on MFMA clusters
  attn_mfma8<<<NHQ * 64, blk, 0, stream>>>(ws_q, ws_kb, ws_vt, cosT, sinT, ws_q);
  // final projection, 128x128 tiles, BK=64 dbuf pipeline
  gemm_out<<<dim3(DMODEL / 128, S_LEN / 128), blk8, 0, stream>>>(ws_q, wqT, out);
}

// Round 14
// 264.490 us; speedup vs baseline: 1.0533x; 1.0533x over previous
//
#include <hip/hip_runtime.h>

#define S_LEN 2048
#define NHQ 32
#define NKV 8
#define HD 64
#define DMODEL 2048   // NHQ*HD
#define DKV 512       // NKV*HD

typedef unsigned short ushort_t;
typedef unsigned int uint_t;

typedef __attribute__((ext_vector_type(8))) short bf16x8;
typedef __attribute__((ext_vector_type(4))) float f32x4;

__device__ __forceinline__ float b2f(ushort_t h) {
  union { uint_t u; float f; } v;
  v.u = ((uint_t)h) << 16;
  return v.f;
}
// round-to-nearest-even fp32 -> bf16
__device__ __forceinline__ ushort_t f2b(float f) {
  union { float f; uint_t u; } v;
  v.f = f;
  uint_t r = v.u + 0x7fffu + ((v.u >> 16) & 1u);
  return (ushort_t)(r >> 16);
}
// HW packed fp32x2 -> bf16x2 (RNE); no builtin on gfx950, inline asm per guide T12
__device__ __forceinline__ uint_t cvt_pk_bf16(float lo, float hi) {
  uint_t r;
  asm("v_cvt_pk_bf16_f32 %0, %1, %2" : "=v"(r) : "v"(lo), "v"(hi));
  return r;
}

union BF8 { uint4 v; ushort_t s[8]; };

// async 16B global -> LDS (wave-uniform LDS base + lane*16)
__device__ __forceinline__ void gl_lds16(const ushort_t* g, ushort_t* l) {
  __builtin_amdgcn_global_load_lds((const __attribute__((address_space(1))) void*)g,
                                   (__attribute__((address_space(3))) void*)l, 16, 0, 0);
}

// 64x64 fp32->bf16 transpose tile body (shared by prework/postproj fusions).
// All 256 threads of the block must enter (contains __syncthreads).
__device__ __forceinline__ void wT_tile(const float* __restrict__ W,
                                        ushort_t* __restrict__ WT,
                                        int K, int N, int r0, int c0,
                                        ushort_t (*T)[66], int tid) {
  {
    const int rl = tid >> 2, cp = (tid & 3) * 16;
    const float* p = W + (size_t)(r0 + rl) * N + c0 + cp;
    float v[16];
    *(float4*)(v)      = *(const float4*)(p);
    *(float4*)(v + 4)  = *(const float4*)(p + 4);
    *(float4*)(v + 8)  = *(const float4*)(p + 8);
    *(float4*)(v + 12) = *(const float4*)(p + 12);
    #pragma unroll
    for (int j = 0; j < 16; ++j) T[cp + j][rl] = f2b(v[j]);
  }
  __syncthreads();
  {
    const int cl = tid >> 2, rp = (tid & 3) * 16;
    uint_t u[8];
    #pragma unroll
    for (int i = 0; i < 8; ++i) u[i] = *(const uint_t*)&T[cl][rp + 2 * i];
    ushort_t* outp = WT + (size_t)(c0 + cl) * K + r0 + rp;
    *(uint4*)(outp)     = make_uint4(u[0], u[1], u[2], u[3]);
    *(uint4*)(outp + 8) = make_uint4(u[4], u[5], u[6], u[7]);
  }
}

// Fused prework: blocks [0,2048) x->bf16; [2048,3072) wq^T; [3072,3328) wk^T;
// [3328,3584) wv^T. Branch is block-uniform; barriers only inside wT_tile.
__global__ __launch_bounds__(256) void prework(const float* __restrict__ X,
                                               ushort_t* __restrict__ XB,
                                               const float* __restrict__ Wq,
                                               const float* __restrict__ Wk,
                                               const float* __restrict__ Wv,
                                               ushort_t* __restrict__ WqT,
                                               ushort_t* __restrict__ WkvT) {
  __shared__ ushort_t T[64][66];
  const int tid = threadIdx.x;
  const int bid = blockIdx.x;
  if (bid < 2048) {
    int i = (bid * 256 + tid) * 8;
    float4 a = *(const float4*)(X + i);
    float4 b = *(const float4*)(X + i + 4);
    BF8 u;
    u.s[0] = f2b(a.x); u.s[1] = f2b(a.y); u.s[2] = f2b(a.z); u.s[3] = f2b(a.w);
    u.s[4] = f2b(b.x); u.s[5] = f2b(b.y); u.s[6] = f2b(b.z); u.s[7] = f2b(b.w);
    *(uint4*)(XB + i) = u.v;
    return;
  }
  const float* W; ushort_t* WT; int N; int local;
  if (bid < 3072)      { local = bid - 2048; W = Wq; WT = WqT;  N = DMODEL; }
  else if (bid < 3328) { local = bid - 3072; W = Wk; WT = WkvT; N = DKV; }
  else                 { local = bid - 3328; W = Wv; WT = WkvT + (size_t)DKV * DMODEL; N = DKV; }
  const int r0 = (local & 31) * 64, c0 = (local >> 5) * 64;
  wT_tile(W, WT, DMODEL, N, r0, c0, T, tid);
}

// Fused post-projection: blocks [0,1024) wo^T (into dead wqT region);
// [1024,3072) rope(K)+KB; [3072,3328) V transpose. All post-gemm_proj deps.
__global__ __launch_bounds__(256) void postproj(const float* __restrict__ Wo,
                                                ushort_t* __restrict__ WoT,
                                                float* Kio, ushort_t* __restrict__ KB,
                                                const float* __restrict__ cosT,
                                                const float* __restrict__ sinT,
                                                const float* __restrict__ V,
                                                ushort_t* __restrict__ VT) {
  __shared__ ushort_t T[64][66];
  const int tid = threadIdx.x;
  const int bid = blockIdx.x;
  if (bid < 1024) {
    const int r0 = (bid & 31) * 64, c0 = (bid >> 5) * 64;
    wT_tile(Wo, WoT, DMODEL, DMODEL, r0, c0, T, tid);
    return;
  }
  if (bid < 3072) {
    int idx = (bid - 1024) * 256 + tid;   // < S*8*32
    int d = idx & 31;
    int hk = (idx >> 5) & 7;
    int s = idx >> 8;
    float* p = Kio + (size_t)s * DKV + hk * HD + d;
    float x1 = p[0], x2 = p[32];
    float c = cosT[s * 64 + d], sn = sinT[s * 64 + d];
    float n1 = x1 * c - x2 * sn;
    float n2 = x1 * sn + x2 * c;
    p[0] = n1; p[32] = n2;
    ushort_t* kb = KB + (size_t)hk * S_LEN * HD + (size_t)s * HD + d;
    kb[0] = f2b(n1); kb[32] = f2b(n2);
    return;
  }
  {
    const int local = bid - 3072;
    const int s0 = (local & 31) * 64;
    const int hk = local >> 5;
    {
      const int s_l = tid >> 2, dp = (tid & 3) * 16;
      const float* p = V + (size_t)(s0 + s_l) * DKV + hk * HD + dp;
      float v[16];
      *(float4*)(v)      = *(const float4*)(p);
      *(float4*)(v + 4)  = *(const float4*)(p + 4);
      *(float4*)(v + 8)  = *(const float4*)(p + 8);
      *(float4*)(v + 12) = *(const float4*)(p + 12);
      #pragma unroll
      for (int j = 0; j < 16; ++j) T[dp + j][s_l] = f2b(v[j]);
    }
    __syncthreads();
    {
      const int d_l = tid >> 2, sp = (tid & 3) * 16;
      uint_t u[8];
      #pragma unroll
      for (int i = 0; i < 8; ++i) u[i] = *(const uint_t*)&T[d_l][sp + 2 * i];
      ushort_t* outp = VT + (size_t)hk * HD * S_LEN + (size_t)d_l * S_LEN + s0 + sp;
      *(uint4*)(outp)     = make_uint4(u[0], u[1], u[2], u[3]);
      *(uint4*)(outp + 8) = make_uint4(u[4], u[5], u[6], u[7]);
    }
  }
}

// GEMM core (round-9 best, exact): 128(M)x128(N) tile, BK=64, 8 waves,
// double-buffered. 32 barrier-drains per block — the proven lever (289->267).
// K-halves stored as separate [128][32] sub-tiles to keep the verified m97
// staging/ds_read layout.
__device__ __forceinline__ void gemm_core_db64(const ushort_t* __restrict__ A,
                                               const ushort_t* __restrict__ BT,
                                               int K, int tile_m, int tile_n,
                                               f32x4 (&acc)[4][2],
                                               ushort_t* AsBase,  // [2][2][128][32]
                                               ushort_t* BsBase) {
  const int tid = threadIdx.x;
  const int lane = tid & 63;
  const int w = tid >> 6;                       // 0..7
  const int wr = (w >> 2) * 64, wc = (w & 3) * 32;
  const int lm = lane & 15, kq = lane >> 4;
  const int BUF = 2 * 128 * 32;                 // ushorts per buffer (2 halves)
  const int HALF = 128 * 32;                    // ushorts per half-tile

  #pragma unroll
  for (int i = 0; i < 4; ++i)
    #pragma unroll
    for (int j = 0; j < 2; ++j) acc[i][j] = {0.f, 0.f, 0.f, 0.f};

  // per-lane global sources; lane l -> row w*16 + (l>>2), k-col (l&3)*8
  const ushort_t* ap = A  + (size_t)(tile_m + w * 16 + (lane >> 2)) * K + (lane & 3) * 8;
  const ushort_t* bp = BT + (size_t)(tile_n + w * 16 + (lane >> 2)) * K + (lane & 3) * 8;
  // wave-uniform LDS stage bases (rows w*16..w*16+15 of each half)
  ushort_t* asw = AsBase + w * 512;
  ushort_t* bsw = BsBase + w * 512;

  // prologue: stage kt=0, both halves, into buf 0
  gl_lds16(ap,      asw);
  gl_lds16(ap + 32, asw + HALF);
  gl_lds16(bp,      bsw);
  gl_lds16(bp + 32, bsw + HALF);
  __syncthreads();                              // buf0 ready

  int cur = 0;
  for (int kt = 0; kt < K; kt += 64) {
    if (kt + 64 < K) {
      const int nb = (cur ^ 1) * BUF;
      gl_lds16(ap + kt + 64, asw + nb);
      gl_lds16(ap + kt + 96, asw + nb + HALF);
      gl_lds16(bp + kt + 64, bsw + nb);
      gl_lds16(bp + kt + 96, bsw + nb + HALF);
    }
    const ushort_t* ac = AsBase + cur * BUF;
    const ushort_t* bc = BsBase + cur * BUF;
    #pragma unroll
    for (int kc = 0; kc < 2; ++kc) {
      bf16x8 af[4], bfr[2];
      #pragma unroll
      for (int i = 0; i < 4; ++i)
        af[i]  = *(const bf16x8*)(ac + kc * HALF + (wr + 16 * i + lm) * 32 + kq * 8);
      #pragma unroll
      for (int j = 0; j < 2; ++j)
        bfr[j] = *(const bf16x8*)(bc + kc * HALF + (wc + 16 * j + lm) * 32 + kq * 8);
      #pragma unroll
      for (int i = 0; i < 4; ++i)
        #pragma unroll
        for (int j = 0; j < 2; ++j)
          acc[i][j] = __builtin_amdgcn_mfma_f32_16x16x32_bf16(af[i], bfr[j], acc[i][j], 0, 0, 0);
    }
    __syncthreads();   // drains vmcnt (next buf staged) + lgkm (cur reads done)
    cur ^= 1;
  }
}

// Fused q/k/v projection: BT = [wqT|wkT|wvT] (N=3072). Split epilogue.
__global__ __launch_bounds__(512) void gemm_proj(const ushort_t* __restrict__ A,
                                                 const ushort_t* __restrict__ BT,
                                                 ushort_t* __restrict__ Qo,
                                                 float* __restrict__ Ko,
                                                 float* __restrict__ Vo) {
  __shared__ ushort_t As[2][2][128][32];
  __shared__ ushort_t Bs[2][2][128][32];
  const int lane = threadIdx.x & 63;
  const int w = threadIdx.x >> 6;
  const int wr = (w >> 2) * 64, wc = (w & 3) * 32;
  const int lm = lane & 15, kq = lane >> 4;
  const int tile_m = blockIdx.y * 128, tile_n = blockIdx.x * 128;
  f32x4 acc[4][2];
  gemm_core_db64(A, BT, DMODEL, tile_m, tile_n, acc, &As[0][0][0][0], &Bs[0][0][0][0]);
  #pragma unroll
  for (int i = 0; i < 4; ++i)
    #pragma unroll
    for (int j = 0; j < 2; ++j)
      #pragma unroll
      for (int r = 0; r < 4; ++r) {
        const int row = tile_m + wr + 16 * i + kq * 4 + r;
        const int col = tile_n + wc + 16 * j + lm;
        const float v = acc[i][j][r];
        if (col < 2048)      Qo[(size_t)row * DMODEL + col] = f2b(v);
        else if (col < 2560) Ko[(size_t)row * DKV + col - 2048] = v;
        else                 Vo[(size_t)row * DKV + col - 2560] = v;
      }
}

// Final projection: C fp32 [M][2048]
__global__ __launch_bounds__(512) void gemm_out(const ushort_t* __restrict__ A,
                                                const ushort_t* __restrict__ BT,
                                                float* __restrict__ C) {
  __shared__ ushort_t As[2][2][128][32];
  __shared__ ushort_t Bs[2][2][128][32];
  const int lane = threadIdx.x & 63;
  const int w = threadIdx.x >> 6;
  const int wr = (w >> 2) * 64, wc = (w & 3) * 32;
  const int lm = lane & 15, kq = lane >> 4;
  const int tile_m = blockIdx.y * 128, tile_n = blockIdx.x * 128;
  f32x4 acc[4][2];
  gemm_core_db64(A, BT, DMODEL, tile_m, tile_n, acc, &As[0][0][0][0], &Bs[0][0][0][0]);
  #pragma unroll
  for (int i = 0; i < 4; ++i)
    #pragma unroll
    for (int j = 0; j < 2; ++j)
      #pragma unroll
      for (int r = 0; r < 4; ++r) {
        const int row = tile_m + wr + 16 * i + kq * 4 + r;
        const int col = tile_n + wc + 16 * j + lm;
        C[(size_t)row * DMODEL + col] = acc[i][j][r];
      }
}

// MFMA flash attention v7 (round-9 best, exact — no setprio; r13 showed T5
// regresses this structure by starving co-resident waves' K/V loads).
// XCD-pinned KV heads: hk = bid&7 -> per-XCD K/V working set 512KB, L2-resident.
__global__ __launch_bounds__(256, 4) void attn_mfma7(const ushort_t* Q,
                                                     const ushort_t* __restrict__ KB,
                                                     const ushort_t* __restrict__ VT,
                                                     const float* __restrict__ cosT,
                                                     const float* __restrict__ sinT,
                                                     ushort_t* O) {
  // union: loop phase Ps[4][32][72] ushort (18432B);
  // combine phase f32 Co[2][64][36] (18432B) + Cm[2][2][64] + Cl[2][2][64] (2048B)
  __shared__ __align__(16) char smem[20480];
  ushort_t (*Ps)[32][72] = (ushort_t (*)[32][72])smem;
  const int wv = threadIdx.x >> 6;          // 0..3
  const int lane = threadIdx.x & 63;
  const int lm = lane & 15, kq = lane >> 4;
  const int bid = blockIdx.x;
  const int xcd = bid & 7;                  // empirical XCD id (bid % 8)
  const int idx = bid >> 3;                 // 0..255 within this XCD
  const int h = (xcd << 2) | (idx & 3);     // hk = h>>2 = xcd: KV pinned to XCD
  const int g = 63 - (idx >> 2);            // LPT within XCD
  const int q0 = g * 32;
  const int hk = h >> 2;
  const ushort_t* KBh = KB + (size_t)hk * S_LEN * HD;
  const ushort_t* VTh = VT + (size_t)hk * HD * S_LEN;
  const float SCL = 0.125f * 1.44269504f;   // /sqrt(64) * log2(e), folded into Q

  // hoisted Q B-frags with in-register RoPE, pre-scaled by SCL
  bf16x8 bq[2][2];
  #pragma unroll
  for (int nt = 0; nt < 2; ++nt) {
    const int row = q0 + 16 * nt + lm;
    const ushort_t* qp = Q + (size_t)row * DMODEL + h * HD + 8 * kq;
    bf16x8 x1v = *(const bf16x8*)qp;
    bf16x8 x2v = *(const bf16x8*)(qp + 32);
    const float* cp = cosT + row * 64 + 8 * kq;
    const float* sp = sinT + row * 64 + 8 * kq;
    float c[8], s[8];
    *(float4*)(c)     = *(const float4*)(cp);
    *(float4*)(c + 4) = *(const float4*)(cp + 4);
    *(float4*)(s)     = *(const float4*)(sp);
    *(float4*)(s + 4) = *(const float4*)(sp + 4);
    BF8 o1, o2;
    #pragma unroll
    for (int j = 0; j < 8; ++j) {
      float x1 = b2f((ushort_t)x1v[j]);
      float x2 = b2f((ushort_t)x2v[j]);
      o1.s[j] = f2b((x1 * c[j] - x2 * s[j]) * SCL);
      o2.s[j] = f2b((x1 * s[j] + x2 * c[j]) * SCL);
    }
    bq[nt][0] = *(const bf16x8*)&o1;
    bq[nt][1] = *(const bf16x8*)&o2;
  }

  f32x4 Oa[4][2];
  #pragma unroll
  for (int mt = 0; mt < 4; ++mt) { Oa[mt][0] = {0.f,0.f,0.f,0.f}; Oa[mt][1] = {0.f,0.f,0.f,0.f}; }
  float m[2] = {-1e30f, -1e30f};
  float l[2] = {0.f, 0.f};                  // per-lane PARTIAL sums (quadrant-local)

  const int ntiles = (g >> 1) + 1;
  for (int t = wv; t < ntiles; t += 4) {
    const int base = t * 64;
    f32x4 sc[4][2];
    #pragma unroll
    for (int mt = 0; mt < 4; ++mt) { sc[mt][0] = {0.f,0.f,0.f,0.f}; sc[mt][1] = {0.f,0.f,0.f,0.f}; }
    #pragma unroll
    for (int kc = 0; kc < 2; ++kc) {
      bf16x8 ak[4];
      #pragma unroll
      for (int mt = 0; mt < 4; ++mt)
        ak[mt] = *(const bf16x8*)&KBh[(size_t)(base + 16 * mt + lm) * HD + 8 * kq + 32 * kc];
      #pragma unroll
      for (int mt = 0; mt < 4; ++mt)
        #pragma unroll
        for (int nt = 0; nt < 2; ++nt)
          sc[mt][nt] = __builtin_amdgcn_mfma_f32_16x16x32_bf16(ak[mt], bq[nt][kc], sc[mt][nt], 0, 0, 0);
    }
    const bool diag = (t == ntiles - 1);
    #pragma unroll
    for (int nt = 0; nt < 2; ++nt) {
      const int qg = q0 + 16 * nt + lm;
      if (diag) {
        #pragma unroll
        for (int mt = 0; mt < 4; ++mt)
          #pragma unroll
          for (int r = 0; r < 4; ++r)
            if (base + 16 * mt + 4 * kq + r > qg) sc[mt][nt][r] = -1e9f;
      }
      // per-lane local max; the __all ballot IS the global defer-max check
      float lmx = sc[0][nt][0];
      #pragma unroll
      for (int mt = 0; mt < 4; ++mt)
        #pragma unroll
        for (int r = 0; r < 4; ++r) lmx = fmaxf(lmx, sc[mt][nt][r]);
      if (!__all(lmx <= m[nt] + 8.f)) {   // rare path: true new max, rescale
        float mx = fmaxf(lmx, __shfl_xor(lmx, 16));
        mx = fmaxf(mx, __shfl_xor(mx, 32));
        const float mn = fmaxf(m[nt], mx);
        const float al = exp2f(m[nt] - mn);
        m[nt] = mn;
        l[nt] *= al;
        #pragma unroll
        for (int mt = 0; mt < 4; ++mt)
          #pragma unroll
          for (int r = 0; r < 4; ++r) Oa[mt][nt][r] *= al;
      }
      float sum = 0.f;
      #pragma unroll
      for (int mt = 0; mt < 4; ++mt)
        #pragma unroll
        for (int r = 0; r < 4; ++r) {
          float p = exp2f(sc[mt][nt][r] - m[nt]);
          sc[mt][nt][r] = p;
          sum += p;
        }
      l[nt] += sum;                        // partial; cross-lane reduce after loop
      ushort_t* pw = &Ps[wv][16 * nt + lm][4 * kq];
      #pragma unroll
      for (int mt = 0; mt < 4; ++mt)
        *(uint2*)(pw + 16 * mt) = make_uint2(cvt_pk_bf16(sc[mt][nt][0], sc[mt][nt][1]),
                                             cvt_pk_bf16(sc[mt][nt][2], sc[mt][nt][3]));
    }
    #pragma unroll
    for (int kc = 0; kc < 2; ++kc) {
      bf16x8 av[4], pb[2];
      #pragma unroll
      for (int mt = 0; mt < 4; ++mt)
        av[mt] = *(const bf16x8*)&VTh[(size_t)(16 * mt + lm) * S_LEN + base + 8 * kq + 32 * kc];
      #pragma unroll
      for (int nt = 0; nt < 2; ++nt)
        pb[nt] = *(const bf16x8*)&Ps[wv][16 * nt + lm][8 * kq + 32 * kc];   // 16B aligned
      #pragma unroll
      for (int mt = 0; mt < 4; ++mt)
        #pragma unroll
        for (int nt = 0; nt < 2; ++nt)
          Oa[mt][nt] = __builtin_amdgcn_mfma_f32_16x16x32_bf16(av[mt], pb[nt], Oa[mt][nt], 0, 0, 0);
    }
  }
  // finalize per-wave l: cross-quadrant sum (once, not per tile)
  #pragma unroll
  for (int nt = 0; nt < 2; ++nt) {
    l[nt] += __shfl_xor(l[nt], 16);
    l[nt] += __shfl_xor(l[nt], 32);
  }

  // ---- two-stage 2-slot flash-combine ----
  float* CoB = (float*)smem;                  // [2][64][36]
  float* CmB = (float*)smem + 2 * 64 * 36;    // [2][2][64]
  float* ClB = CmB + 2 * 2 * 64;              // [2][2][64]
  __syncthreads();                            // all Ps reads done; smem reused
  if (wv & 1) {                               // waves 1,3 store
    const int slot = wv >> 1;
    float* myo = CoB + (size_t)(slot * 64 + lane) * 36;
    #pragma unroll
    for (int mt = 0; mt < 4; ++mt)
      #pragma unroll
      for (int nt = 0; nt < 2; ++nt)
        *(f32x4*)(myo + (mt * 2 + nt) * 4) = Oa[mt][nt];
    #pragma unroll
    for (int nt = 0; nt < 2; ++nt) {
      CmB[(slot * 2 + nt) * 64 + lane] = m[nt];
      ClB[(slot * 2 + nt) * 64 + lane] = l[nt];
    }
  }
  __syncthreads();
  if (!(wv & 1)) {                            // waves 0,2 merge their slot
    const int slot = wv >> 1;
    const float* po = CoB + (size_t)(slot * 64 + lane) * 36;
    #pragma unroll
    for (int nt = 0; nt < 2; ++nt) {
      const float m1 = CmB[(slot * 2 + nt) * 64 + lane];
      const float l1 = ClB[(slot * 2 + nt) * 64 + lane];
      const float mn = fmaxf(m[nt], m1);
      const float a0 = exp2f(m[nt] - mn);
      const float a1 = exp2f(m1 - mn);
      m[nt] = mn;
      l[nt] = l[nt] * a0 + l1 * a1;
      #pragma unroll
      for (int mt = 0; mt < 4; ++mt) {
        const f32x4 ov = *(const f32x4*)(po + (mt * 2 + nt) * 4);
        #pragma unroll
        for (int r = 0; r < 4; ++r) Oa[mt][nt][r] = Oa[mt][nt][r] * a0 + ov[r] * a1;
      }
    }
  }
  __syncthreads();
  if (wv == 2) {                              // stage 2 store
    float* myo = CoB + (size_t)lane * 36;
    #pragma unroll
    for (int mt = 0; mt < 4; ++mt)
      #pragma unroll
      for (int nt = 0; nt < 2; ++nt)
        *(f32x4*)(myo + (mt * 2 + nt) * 4) = Oa[mt][nt];
    #pragma unroll
    for (int nt = 0; nt < 2; ++nt) {
      CmB[nt * 64 + lane] = m[nt];
      ClB[nt * 64 + lane] = l[nt];
    }
  }
  __syncthreads();
  if (wv == 0) {                              // final merge + output
    const float* po = CoB + (size_t)lane * 36;
    #pragma unroll
    for (int nt = 0; nt < 2; ++nt) {
      const float m1 = CmB[nt * 64 + lane];
      const float l1 = ClB[nt * 64 + lane];
      const float mn = fmaxf(m[nt], m1);
      const float a0 = exp2f(m[nt] - mn);
      const float a1 = exp2f(m1 - mn);
      const float inv = 1.f / (l[nt] * a0 + l1 * a1);
      ushort_t* orow = O + (size_t)(q0 + 16 * nt + lm) * DMODEL + h * HD + 4 * kq;
      #pragma unroll
      for (int mt = 0; mt < 4; ++mt) {
        const f32x4 ov = *(const f32x4*)(po + (mt * 2 + nt) * 4);
        const float v0 = (Oa[mt][nt][0] * a0 + ov[0] * a1) * inv;
        const float v1 = (Oa[mt][nt][1] * a0 + ov[1] * a1) * inv;
        const float v2 = (Oa[mt][nt][2] * a0 + ov[2] * a1) * inv;
        const float v3 = (Oa[mt][nt][3] * a0 + ov[3] * a1) * inv;
        *(uint2*)(orow + 16 * mt) = make_uint2(cvt_pk_bf16(v0, v1), cvt_pk_bf16(v2, v3));
      }
    }
  }
}

extern "C" void kernel_launch(void* const* d_in, const int* in_sizes, int n_in,
                              void* d_out, int out_size, void* d_ws, size_t ws_size,
                              hipStream_t stream) {
  const float* x    = (const float*)d_in[0];
  const float* cosT = (const float*)d_in[1];
  const float* sinT = (const float*)d_in[2];
  // d_in[3] = mask: causal -1e9, applied analytically (identical semantics)
  const float* wq   = (const float*)d_in[4];
  const float* wk   = (const float*)d_in[5];
  const float* wv   = (const float*)d_in[6];
  const float* wo   = (const float*)d_in[7];

  float* out   = (float*)d_out;                    // [S, 2048] fp32
  float* out_k = out + (size_t)S_LEN * DMODEL;     // new_k [S, 8, 64] fp32
  float* out_v = out_k + (size_t)S_LEN * DKV;      // new_v [S, 8, 64] fp32

  const size_t MB = 1024 * 1024;
  ushort_t* ws    = (ushort_t*)d_ws;               // ws_size >= 24 MB (confirmed r8)
  ushort_t* wqT   = ws;                            // [0,8M)  wqT bf16 [2048][2048]; later woT
  ushort_t* wkT   = ws + 4 * MB;                   // [8,10M) wkT; wvT follows -> BT [3072][2048]
  ushort_t* ws_q  = ws + 6 * MB;                   // [12,20M) q bf16 [S][2048]
  ushort_t* ws_kb = ws + 10 * MB;                  // [20,22M) KB bf16 [8][S][64]
  ushort_t* ws_vt = ws + 11 * MB;                  // [22,24M) VT bf16 [8][64][S]
  ushort_t* xb    = (ushort_t*)out;                // scratch in dead out region

  dim3 blk(256);
  dim3 blk8(512);
  // fused prework: x->bf16 + wq/wk/wv transposes (1 launch)
  prework<<<3584, blk, 0, stream>>>(x, xb, wq, wk, wv, wqT, wkT);
  // fused q/k/v projection (N = 3072), 128x128 tiles, BK=64 dbuf pipeline
  gemm_proj<<<dim3(3072 / 128, S_LEN / 128), blk8, 0, stream>>>(xb, wqT, ws_q, out_k, out_v);
  // fused post-proj: wo^T (into dead wqT) + rope(K)+KB + V transpose (1 launch)
  postproj<<<3328, blk, 0, stream>>>(wo, wqT, out_k, ws_kb, cosT, sinT, out_v, ws_vt);
  // attention v7: XCD-pinned KV heads (hk = bid&7), L2-resident K/V
  attn_mfma7<<<NHQ * 64, blk, 0, stream>>>(ws_q, ws_kb, ws_vt, cosT, sinT, ws_q);
  // final projection, 128x128 tiles, BK=64 dbuf pipeline
  gemm_out<<<dim3(DMODEL / 128, S_LEN / 128), blk8, 0, stream>>>(ws_q, wqT, out);
}